// Round 2
// baseline (23598.329 us; speedup 1.0000x reference)
//
#include <hip/hip_runtime.h>

// ---------------------------------------------------------------------------
// VGG16-3D forward, fp32, channels-last (NDHWC).
// R1: fit workspace under 192.5 MiB (R0 crash = 256MiB ws overflow theory).
//   - conv2 split over batch to avoid 2x128MiB ping-pong
//   - BN affine+ReLU fused into maxpool output (monotone-affine commutes w/ max)
// ---------------------------------------------------------------------------

// ---------------- conv3d, Cin % 4 == 0, Co % 64 == 0 -----------------------
__global__ __launch_bounds__(256) void conv3d_vec4(
    const float* __restrict__ x, const float* __restrict__ w, float* __restrict__ out,
    int N, int X, int Y, int Z, int Cin, int Co)
{
  const int tid = threadIdx.x;
  const int tx = tid & 63;          // co lane
  const int ty = tid >> 6;          // voxel wave 0..3
  const int co = blockIdx.y * 64 + tx;
  const long nvox = (long)N * X * Y * Z;
  const long vbase = (long)blockIdx.x * 32;

  int cn[8], cx[8], cy[8], cz[8];
  #pragma unroll
  for (int k = 0; k < 8; ++k) {
    long v = vbase + ty + 4L * k;
    long vv = (v < nvox) ? v : 0;
    cz[k] = (int)(vv % Z); vv /= Z;
    cy[k] = (int)(vv % Y); vv /= Y;
    cx[k] = (int)(vv % X); vv /= X;
    cn[k] = (int)vv;
    if (v >= nvox) cn[k] = -1;      // dead voxel
  }

  float acc[8];
  #pragma unroll
  for (int k = 0; k < 8; ++k) acc[k] = 0.f;

  for (int t = 0; t < 27; ++t) {
    const int k0 = t / 9, k1 = (t / 3) % 3, k2 = t % 3;
    const float* wt = w + (long)t * Cin * Co + co;
    long soff[8];
    #pragma unroll
    for (int k = 0; k < 8; ++k) {
      const int sx = cx[k] + k0 - 1, sy = cy[k] + k1 - 1, sz = cz[k] + k2 - 1;
      const bool ok = (cn[k] >= 0) && sx >= 0 && sx < X && sy >= 0 && sy < Y
                      && sz >= 0 && sz < Z;
      soff[k] = ok ? ((((long)cn[k] * X + sx) * Y + sy) * Z + sz) * (long)Cin : -1L;
    }
    for (int ci = 0; ci < Cin; ci += 4) {
      const float w0 = wt[(long)(ci + 0) * Co];
      const float w1 = wt[(long)(ci + 1) * Co];
      const float w2 = wt[(long)(ci + 2) * Co];
      const float w3 = wt[(long)(ci + 3) * Co];
      #pragma unroll
      for (int k = 0; k < 8; ++k) {
        if (soff[k] >= 0) {
          const float4 xv = *reinterpret_cast<const float4*>(x + soff[k] + ci);
          float a = acc[k];
          a = fmaf(xv.x, w0, a);
          a = fmaf(xv.y, w1, a);
          a = fmaf(xv.z, w2, a);
          a = fmaf(xv.w, w3, a);
          acc[k] = a;
        }
      }
    }
  }
  #pragma unroll
  for (int k = 0; k < 8; ++k) {
    long v = vbase + ty + 4L * k;
    if (v < nvox) out[v * (long)Co + co] = acc[k];
  }
}

// ---------------- conv3d, Cin == 3 (first layer) ----------------------------
__global__ __launch_bounds__(256) void conv3d_c3(
    const float* __restrict__ x, const float* __restrict__ w, float* __restrict__ out,
    int N, int X, int Y, int Z, int Co)
{
  const int tid = threadIdx.x;
  const int tx = tid & 63;
  const int ty = tid >> 6;
  const int co = blockIdx.y * 64 + tx;
  const long nvox = (long)N * X * Y * Z;
  const long vbase = (long)blockIdx.x * 32;

  int cn[8], cx[8], cy[8], cz[8];
  #pragma unroll
  for (int k = 0; k < 8; ++k) {
    long v = vbase + ty + 4L * k;
    long vv = (v < nvox) ? v : 0;
    cz[k] = (int)(vv % Z); vv /= Z;
    cy[k] = (int)(vv % Y); vv /= Y;
    cx[k] = (int)(vv % X); vv /= X;
    cn[k] = (int)vv;
    if (v >= nvox) cn[k] = -1;
  }

  float acc[8];
  #pragma unroll
  for (int k = 0; k < 8; ++k) acc[k] = 0.f;

  for (int t = 0; t < 27; ++t) {
    const int k0 = t / 9, k1 = (t / 3) % 3, k2 = t % 3;
    const float* wt = w + (long)t * 3 * Co + co;
    const float w0 = wt[0];
    const float w1 = wt[Co];
    const float w2 = wt[2L * Co];
    #pragma unroll
    for (int k = 0; k < 8; ++k) {
      const int sx = cx[k] + k0 - 1, sy = cy[k] + k1 - 1, sz = cz[k] + k2 - 1;
      const bool ok = (cn[k] >= 0) && sx >= 0 && sx < X && sy >= 0 && sy < Y
                      && sz >= 0 && sz < Z;
      if (ok) {
        const long soff = ((((long)cn[k] * X + sx) * Y + sy) * Z + sz) * 3L;
        float a = acc[k];
        a = fmaf(x[soff + 0], w0, a);
        a = fmaf(x[soff + 1], w1, a);
        a = fmaf(x[soff + 2], w2, a);
        acc[k] = a;
      }
    }
  }
  #pragma unroll
  for (int k = 0; k < 8; ++k) {
    long v = vbase + ty + 4L * k;
    if (v < nvox) out[v * (long)Co + co] = acc[k];
  }
}

// ------- per-channel sum / sumsq partials, two-fragment input (determ.) ----
#define NB_STATS 256
__global__ __launch_bounds__(256) void stats_partial(
    const float* __restrict__ p0, const float* __restrict__ p1, long n0, long ntot,
    int C, float* __restrict__ part)
{
  const int tid = threadIdx.x;
  const int ng = 256 / C;               // C in {64,128,256}
  const int c = tid % C;
  const int g = tid / C;
  float s = 0.f, ss = 0.f;
  for (long v = (long)blockIdx.x * ng + g; v < ntot; v += (long)gridDim.x * ng) {
    const float* p = (v < n0) ? (p0 + v * (long)C) : (p1 + (v - n0) * (long)C);
    const float val = p[c];
    s += val;
    ss = fmaf(val, val, ss);
  }
  __shared__ float sh0[256];
  __shared__ float sh1[256];
  sh0[tid] = s; sh1[tid] = ss;
  __syncthreads();
  if (tid < C) {
    for (int g2 = 1; g2 < ng; ++g2) { s += sh0[tid + g2 * C]; ss += sh1[tid + g2 * C]; }
    part[(long)blockIdx.x * 2 * C + tid] = s;
    part[(long)blockIdx.x * 2 * C + C + tid] = ss;
  }
}

// ---------------- finalize: per-channel scale/shift -------------------------
__global__ __launch_bounds__(256) void stats_final(
    const float* __restrict__ part, int nb, int C, long nvox,
    const float* __restrict__ g, const float* __restrict__ b,
    float* __restrict__ sc, float* __restrict__ sh)
{
  const int c = threadIdx.x;
  if (c >= C) return;
  float s = 0.f, ss = 0.f;
  for (int i = 0; i < nb; ++i) {
    s += part[(long)i * 2 * C + c];
    ss += part[(long)i * 2 * C + C + c];
  }
  const float inv = 1.f / (float)nvox;
  const float m = s * inv;
  const float var = ss * inv - m * m;
  const float scale = rsqrtf(var + 1e-5f) * g[c];
  sc[c] = scale;
  sh[c] = b[c] - m * scale;
}

// ---------------- fused BN affine + ReLU, in-place capable -----------------
__global__ __launch_bounds__(256) void bn_act(
    const float* __restrict__ in, float* __restrict__ out,
    const float* __restrict__ sc, const float* __restrict__ sh,
    long nelem, int C)
{
  long i = ((long)blockIdx.x * 256 + threadIdx.x) * 4;
  const long stride = (long)gridDim.x * 1024;
  for (; i < nelem; i += stride) {
    const float4 v = *reinterpret_cast<const float4*>(in + i);
    const int c = (int)(i % C);          // i % 4 == 0 and C % 4 == 0
    const float4 s4 = *reinterpret_cast<const float4*>(sc + c);
    const float4 h4 = *reinterpret_cast<const float4*>(sh + c);
    float4 r;
    r.x = fmaxf(fmaf(v.x, s4.x, h4.x), 0.f);
    r.y = fmaxf(fmaf(v.y, s4.y, h4.y), 0.f);
    r.z = fmaxf(fmaf(v.z, s4.z, h4.z), 0.f);
    r.w = fmaxf(fmaf(v.w, s4.w, h4.w), 0.f);
    *reinterpret_cast<float4*>(out + i) = r;
  }
}

// ------- 2x2x2 max pool on RAW conv output, then BN affine + ReLU ----------
// maxpool(relu(bn(x))) == relu(bn(maxpool(x))) since bn scale > 0 here.
__global__ __launch_bounds__(256) void maxpool2_aff(
    const float* __restrict__ in, float* __restrict__ out,
    int N, int X, int Y, int Z, int C,
    const float* __restrict__ sc, const float* __restrict__ sh)
{
  const int OX = X >> 1, OY = Y >> 1, OZ = Z >> 1;
  const int c4n = C >> 2;
  const long nout = (long)N * OX * OY * OZ * c4n;
  long idx = (long)blockIdx.x * 256 + threadIdx.x;
  if (idx >= nout) return;
  const int c4 = (int)(idx % c4n);
  long v = idx / c4n;
  const int oz = (int)(v % OZ); v /= OZ;
  const int oy = (int)(v % OY); v /= OY;
  const int ox = (int)(v % OX);
  const int n = (int)(v / OX);
  const long sx = (long)Y * Z * C, sy = (long)Z * C, sz = C;
  const long base = ((((long)n * X + 2 * ox) * Y + 2 * oy) * Z + 2 * oz) * (long)C + 4L * c4;
  float4 m = *reinterpret_cast<const float4*>(in + base);
  #pragma unroll
  for (int dd = 1; dd < 8; ++dd) {
    const int dx = dd >> 2, dy = (dd >> 1) & 1, dz = dd & 1;
    const float4 t = *reinterpret_cast<const float4*>(in + base + dx * sx + dy * sy + dz * sz);
    m.x = fmaxf(m.x, t.x); m.y = fmaxf(m.y, t.y);
    m.z = fmaxf(m.z, t.z); m.w = fmaxf(m.w, t.w);
  }
  const int c = 4 * c4;
  const float4 s4 = *reinterpret_cast<const float4*>(sc + c);
  const float4 h4 = *reinterpret_cast<const float4*>(sh + c);
  m.x = fmaxf(fmaf(m.x, s4.x, h4.x), 0.f);
  m.y = fmaxf(fmaf(m.y, s4.y, h4.y), 0.f);
  m.z = fmaxf(fmaf(m.z, s4.z, h4.z), 0.f);
  m.w = fmaxf(fmaf(m.w, s4.w, h4.w), 0.f);
  *reinterpret_cast<float4*>(out + idx * 4) = m;
}

// ---------------- head: BN8(affine) -> global mean -> linear ----------------
__global__ __launch_bounds__(256) void head_kernel(
    const float* __restrict__ x8, const float* __restrict__ sc, const float* __restrict__ sh,
    const float* __restrict__ wl, const float* __restrict__ bl, float* __restrict__ out)
{
  const int n = blockIdx.x;
  const int c = threadIdx.x;     // 256
  __shared__ float h[256];
  const float* base = x8 + (long)n * 512 * 256;
  float s = 0.f;
  for (int v = 0; v < 512; ++v) s += base[(long)v * 256 + c];
  // mean is affine-commutable with BN: bn(mean(x)) == mean(bn(x))
  h[c] = fmaf(s * (1.f / 512.f), sc[c], sh[c]);
  __syncthreads();
  float acc = bl[c];
  for (int k = 0; k < 256; ++k) acc = fmaf(h[k], wl[(long)k * 256 + c], acc);
  out[(long)n * 256 + c] = acc;
}

// ---------------------------------------------------------------------------
extern "C" void kernel_launch(void* const* d_in, const int* in_sizes, int n_in,
                              void* d_out, int out_size, void* d_ws, size_t ws_size,
                              hipStream_t stream)
{
  const float* x = (const float*)d_in[0];
  const float* W[8];
  const float* G[8];
  const float* B[8];
  for (int i = 0; i < 8; ++i) {
    W[i] = (const float*)d_in[1 + 3 * i];
    G[i] = (const float*)d_in[2 + 3 * i];
    B[i] = (const float*)d_in[3 + 3 * i];
  }
  const float* wl = (const float*)d_in[25];
  const float* bl = (const float*)d_in[26];

  // workspace carve-up (floats): total 50,463,232 fl = 192.5 MiB
  float* A    = (float*)d_ws;                 // 33,554,432 fl (128 MiB)
  float* Bb   = A + 33554432L;                // 16,777,216 fl ( 64 MiB)
  float* part = Bb + 16777216L;               // 131,072 fl
  float* scb  = part + 131072L;               // 256
  float* shb  = scb + 256;                    // 256

  auto conv = [&](const float* in, float* ob, const float* w,
                  int N, int Xd, int Yd, int Zd, int Cin, int Co) {
    const long nvox = (long)N * Xd * Yd * Zd;
    dim3 grid((unsigned)((nvox + 31) / 32), (unsigned)(Co / 64));
    if (Cin == 3)
      conv3d_c3<<<grid, 256, 0, stream>>>(in, w, ob, N, Xd, Yd, Zd, Co);
    else
      conv3d_vec4<<<grid, 256, 0, stream>>>(in, w, ob, N, Xd, Yd, Zd, Cin, Co);
  };

  auto stats = [&](const float* p0, const float* p1, long n0, long ntot, int C, int layer) {
    stats_partial<<<NB_STATS, 256, 0, stream>>>(p0, p1, n0, ntot, C, part);
    stats_final<<<1, 256, 0, stream>>>(part, NB_STATS, C, ntot, G[layer], B[layer], scb, shb);
  };

  auto bnrelu = [&](float* t, long nelem, int C) {
    long nb = (nelem / 4 + 255) / 256;
    if (nb > 8192) nb = 8192;
    bn_act<<<(unsigned)nb, 256, 0, stream>>>(t, t, scb, shb, nelem, C);
  };

  auto pool_aff = [&](const float* in, float* ob, int N, int Xd, int Yd, int Zd, int C) {
    const long nout = (long)N * (Xd / 2) * (Yd / 2) * (Zd / 2) * (C / 4);
    maxpool2_aff<<<(unsigned)((nout + 255) / 256), 256, 0, stream>>>(
        in, ob, N, Xd, Yd, Zd, C, scb, shb);
  };

  const long V64 = 262144;   // 64^3 voxels (one batch item)

  // ---- stage 1: 64^3 ----
  conv(x, A, W[0], 2, 64, 64, 64, 3, 64);
  stats(A, A, 2 * V64, 2 * V64, 64, 0);
  bnrelu(A, 2 * V64 * 64, 64);
  // conv2 split over batch: b0 -> Bb, b1 -> A[0:16M] (reads A[16M:32M], disjoint)
  conv(A,             Bb, W[1], 1, 64, 64, 64, 64, 64);
  conv(A + V64 * 64,  A,  W[1], 1, 64, 64, 64, 64, 64);
  stats(Bb, A, V64, 2 * V64, 64, 1);
  // pooled stage-1 output P = A[16M : 16M+4M], packed b0 then b1
  {
    float* P = A + 16777216L;
    pool_aff(Bb, P,            1, 64, 64, 64, 64);
    pool_aff(A,  P + 2097152L, 1, 64, 64, 64, 64);
  }

  // ---- stage 2: 32^3 ----
  const float* P1 = A + 16777216L;            // 2*32^3*64 = 4M fl
  conv(P1, A, W[2], 2, 32, 32, 32, 64, 128);  // out A[0 : 8,388,608]
  stats(A, A, 65536, 65536, 128, 2);
  bnrelu(A, 65536L * 128, 128);
  conv(A, Bb, W[3], 2, 32, 32, 32, 128, 128); // out Bb[0 : 8,388,608]
  stats(Bb, Bb, 65536, 65536, 128, 3);
  float* Q = A + 8388608L;                    // pooled: 2*16^3*128 = 1,048,576 fl
  pool_aff(Bb, Q, 2, 32, 32, 32, 128);

  // ---- stage 3: 16^3 ----
  conv(Q, A, W[4], 2, 16, 16, 16, 128, 256);  // out A[0 : 2,097,152]
  stats(A, A, 8192, 8192, 256, 4);
  bnrelu(A, 8192L * 256, 256);
  conv(A, Bb, W[5], 2, 16, 16, 16, 256, 256); // out Bb[0 : 2,097,152]
  stats(Bb, Bb, 8192, 8192, 256, 5);
  bnrelu(Bb, 8192L * 256, 256);
  float* A2 = A + 2097152L;
  conv(Bb, A2, W[6], 2, 16, 16, 16, 256, 256); // out A[2M : 4.2M]
  stats(A2, A2, 8192, 8192, 256, 6);
  float* R = A;                                // pooled: 2*8^3*256 = 262,144 fl
  pool_aff(A2, R, 2, 16, 16, 16, 256);

  // ---- stage 4: 8^3, conv8 + BN (no ReLU) folded into head ----
  conv(R, Bb, W[7], 2, 8, 8, 8, 256, 256);     // out Bb[0 : 262,144]
  stats(Bb, Bb, 1024, 1024, 256, 7);
  head_kernel<<<2, 256, 0, stream>>>(Bb, scb, shb, wl, bl, (float*)d_out);
}

// Round 3
// 1745.818 us; speedup vs baseline: 13.5171x; 13.5171x over previous
//
#include <hip/hip_runtime.h>

// ---------------------------------------------------------------------------
// VGG16-3D forward. R2: all convs via f16 MFMA implicit GEMM (16x16x32),
// fp32 activations in global, f16 LDS slab with zero-pad boundary rows,
// weights pre-packed into MFMA fragment order. Stats/BN/pool/head from R1.
// ---------------------------------------------------------------------------

typedef _Float16 f16;
typedef _Float16 f16x8 __attribute__((ext_vector_type(8)));
typedef float f32x4 __attribute__((ext_vector_type(4)));

// ---------------- weight prep: [27][CinR][Co] f32 -> fragment-packed f16 ----
// layout: [t][s][g][lane][i] ; k = s*32 + (lane>>4)*8 + i ; co = g*16 + (lane&15)
__global__ __launch_bounds__(256) void wprep(
    const float* __restrict__ w, f16* __restrict__ wf,
    int S, int G, int CinReal, int Co, int ntot)
{
  int e = blockIdx.x * 256 + threadIdx.x;
  if (e >= ntot) return;
  const int i = e & 7;
  const int l = (e >> 3) & 63;
  int r = e >> 9;
  const int g = r % G; r /= G;
  const int s = r % S; r /= S;
  const int t = r;
  const int k = s * 32 + ((l >> 4) << 3) + i;
  const int co = g * 16 + (l & 15);
  float v = (k < CinReal) ? w[((long)t * CinReal + k) * Co + co] : 0.f;
  wf[e] = (f16)v;
}

// ---------------- implicit-GEMM conv3d via mfma_f32_16x16x32_f16 -----------
template<int CIN, int CINR, int Z, int WR, int WC>
__global__ __launch_bounds__(WR*WC*64) void conv_mfma(
    const float* __restrict__ xin, const f16* __restrict__ wf,
    float* __restrict__ out, int X, int Y, int Co)
{
  constexpr int NTHR = WR * WC * 64;
  constexpr int L = 64 * WR / Z;          // z-lines per block
  constexpr int RB = (CIN + 8) * 2;       // LDS row bytes (+8 f16 pad)
  constexpr int S = CIN / 32;             // K-steps per tap
  __shared__ __align__(16) char slab[(L + 2) * (Z + 2) * RB];

  const int tid = threadIdx.x;
  const int lane = tid & 63;
  const int wv = tid >> 6;
  const int wr = wv / WC, wc = wv % WC;

  const long vb = (long)blockIdx.x * (64 * WR);
  const int XYZ = X * Y * Z;
  const int n = (int)(vb / XYZ);
  const int rem = (int)(vb % XYZ);
  const int x0 = rem / (Y * Z);
  const int y0 = (rem % (Y * Z)) / Z;
  const int co0 = blockIdx.y * (64 * WC);
  const int Gtot = Co >> 4;
  const int g0 = (co0 >> 4) + wc * 4;

  // per-lane A base byte offsets, one per 16-row group
  int abase[4];
  #pragma unroll
  for (int r = 0; r < 4; ++r) {
    const int vl = wr * 64 + r * 16 + (lane & 15);
    const int ly = vl / Z, z = vl % Z;
    abase[r] = (ly * (Z + 2) + z) * RB + ((lane >> 4) << 4);
  }

  f32x4 acc[4][4];
  const f32x4 fz = {0.f, 0.f, 0.f, 0.f};
  #pragma unroll
  for (int r = 0; r < 4; ++r)
    #pragma unroll
    for (int c = 0; c < 4; ++c) acc[r][c] = fz;

  // zero the z-pad rows (once; never overwritten by staging)
  {
    const f16x8 hz = {};
    for (int e = tid * 8; e < (L + 2) * 2 * CIN; e += NTHR * 8) {
      const int pr = e / CIN, ci = e % CIN;
      const int row = (pr >> 1) * (Z + 2) + (pr & 1) * (Z + 1);
      *(f16x8*)(slab + row * RB + ci * 2) = hz;
    }
  }

  for (int dx = 0; dx < 3; ++dx) {
    __syncthreads();
    const int xs = x0 + dx - 1;
    const bool xok = (xs >= 0) && (xs < X);
    const long gv0 = ((long)(n * X + xs) * Y + (y0 - 1)) * Z;  // voxel of slab row 0

    if constexpr (CINR == CIN) {
      constexpr int NE = (L + 2) * Z * CIN;
      for (int e = tid * 8; e < NE; e += NTHR * 8) {
        const int rr = e / CIN, ci = e % CIN;
        const int li = rr / Z, z = rr % Z;
        const int ys = y0 - 1 + li;
        f16x8 h = {};
        if (xok && ys >= 0 && ys < Y) {
          const float* p = xin + (gv0 + rr) * CIN + ci;
          const float4 v0 = *(const float4*)p;
          const float4 v1 = *(const float4*)(p + 4);
          h[0] = (f16)v0.x; h[1] = (f16)v0.y; h[2] = (f16)v0.z; h[3] = (f16)v0.w;
          h[4] = (f16)v1.x; h[5] = (f16)v1.y; h[6] = (f16)v1.z; h[7] = (f16)v1.w;
        }
        *(f16x8*)(slab + (li * (Z + 2) + 1 + z) * RB + ci * 2) = h;
      }
    } else {
      // conv1: CINR(=3) real channels, padded to CIN
      for (int rr = tid; rr < (L + 2) * Z; rr += NTHR) {
        const int li = rr / Z, z = rr % Z;
        const int ys = y0 - 1 + li;
        f16x8 h = {};
        if (xok && ys >= 0 && ys < Y) {
          const float* p = xin + (gv0 + rr) * CINR;
          #pragma unroll
          for (int i = 0; i < CINR; ++i) h[i] = (f16)p[i];
        }
        char* drow = slab + (li * (Z + 2) + 1 + z) * RB;
        *(f16x8*)drow = h;
        const f16x8 hz = {};
        #pragma unroll
        for (int ch = 1; ch < CIN / 8; ++ch) *(f16x8*)(drow + ch * 16) = hz;
      }
    }
    __syncthreads();

    for (int s = 0; s < S; ++s) {
      #pragma unroll
      for (int dy = 0; dy < 3; ++dy) {
        #pragma unroll
        for (int dzi = 0; dzi < 3; ++dzi) {
          f16x8 av[4];
          #pragma unroll
          for (int r = 0; r < 4; ++r)
            av[r] = *(const f16x8*)(slab + abase[r] + s * 64 + (dy * (Z + 2) + dzi) * RB);
          const int t = dx * 9 + dy * 3 + dzi;
          f16x8 bv[4];
          #pragma unroll
          for (int c = 0; c < 4; ++c)
            bv[c] = *(const f16x8*)((const char*)wf +
                      (((long)(t * S + s) * Gtot + g0 + c) << 10) + (lane << 4));
          #pragma unroll
          for (int r = 0; r < 4; ++r)
            #pragma unroll
            for (int c = 0; c < 4; ++c)
              acc[r][c] = __builtin_amdgcn_mfma_f32_16x16x32_f16(av[r], bv[c], acc[r][c], 0, 0, 0);
        }
      }
    }
  }

  // epilogue: D col = lane&15 (co), row = (lane>>4)*4 + q (vox)
  const long vgbase = vb + wr * 64;
  const int cobase = co0 + wc * 64;
  #pragma unroll
  for (int r = 0; r < 4; ++r)
    #pragma unroll
    for (int c = 0; c < 4; ++c)
      #pragma unroll
      for (int q = 0; q < 4; ++q) {
        const long vox = vgbase + r * 16 + ((lane >> 4) << 2) + q;
        const int co = cobase + c * 16 + (lane & 15);
        out[vox * Co + co] = acc[r][c][q];
      }
}

// ------- per-channel sum / sumsq partials, two-fragment input (determ.) ----
#define NB_STATS 256
__global__ __launch_bounds__(256) void stats_partial(
    const float* __restrict__ p0, const float* __restrict__ p1, long n0, long ntot,
    int C, float* __restrict__ part)
{
  const int tid = threadIdx.x;
  const int ng = 256 / C;
  const int c = tid % C;
  const int g = tid / C;
  float s = 0.f, ss = 0.f;
  for (long v = (long)blockIdx.x * ng + g; v < ntot; v += (long)gridDim.x * ng) {
    const float* p = (v < n0) ? (p0 + v * (long)C) : (p1 + (v - n0) * (long)C);
    const float val = p[c];
    s += val;
    ss = fmaf(val, val, ss);
  }
  __shared__ float sh0[256];
  __shared__ float sh1[256];
  sh0[tid] = s; sh1[tid] = ss;
  __syncthreads();
  if (tid < C) {
    for (int g2 = 1; g2 < ng; ++g2) { s += sh0[tid + g2 * C]; ss += sh1[tid + g2 * C]; }
    part[(long)blockIdx.x * 2 * C + tid] = s;
    part[(long)blockIdx.x * 2 * C + C + tid] = ss;
  }
}

__global__ __launch_bounds__(256) void stats_final(
    const float* __restrict__ part, int nb, int C, long nvox,
    const float* __restrict__ g, const float* __restrict__ b,
    float* __restrict__ sc, float* __restrict__ sh)
{
  const int c = threadIdx.x;
  if (c >= C) return;
  float s = 0.f, ss = 0.f;
  for (int i = 0; i < nb; ++i) {
    s += part[(long)i * 2 * C + c];
    ss += part[(long)i * 2 * C + C + c];
  }
  const float inv = 1.f / (float)nvox;
  const float m = s * inv;
  const float var = ss * inv - m * m;
  const float scale = rsqrtf(var + 1e-5f) * g[c];
  sc[c] = scale;
  sh[c] = b[c] - m * scale;
}

__global__ __launch_bounds__(256) void bn_act(
    const float* __restrict__ in, float* __restrict__ out,
    const float* __restrict__ sc, const float* __restrict__ sh,
    long nelem, int C)
{
  long i = ((long)blockIdx.x * 256 + threadIdx.x) * 4;
  const long stride = (long)gridDim.x * 1024;
  for (; i < nelem; i += stride) {
    const float4 v = *reinterpret_cast<const float4*>(in + i);
    const int c = (int)(i % C);
    const float4 s4 = *reinterpret_cast<const float4*>(sc + c);
    const float4 h4 = *reinterpret_cast<const float4*>(sh + c);
    float4 r;
    r.x = fmaxf(fmaf(v.x, s4.x, h4.x), 0.f);
    r.y = fmaxf(fmaf(v.y, s4.y, h4.y), 0.f);
    r.z = fmaxf(fmaf(v.z, s4.z, h4.z), 0.f);
    r.w = fmaxf(fmaf(v.w, s4.w, h4.w), 0.f);
    *reinterpret_cast<float4*>(out + i) = r;
  }
}

// maxpool(relu(bn(x))) == relu(bn(maxpool(x))) since bn scale > 0 here.
__global__ __launch_bounds__(256) void maxpool2_aff(
    const float* __restrict__ in, float* __restrict__ out,
    int N, int X, int Y, int Z, int C,
    const float* __restrict__ sc, const float* __restrict__ sh)
{
  const int OX = X >> 1, OY = Y >> 1, OZ = Z >> 1;
  const int c4n = C >> 2;
  const long nout = (long)N * OX * OY * OZ * c4n;
  long idx = (long)blockIdx.x * 256 + threadIdx.x;
  if (idx >= nout) return;
  const int c4 = (int)(idx % c4n);
  long v = idx / c4n;
  const int oz = (int)(v % OZ); v /= OZ;
  const int oy = (int)(v % OY); v /= OY;
  const int ox = (int)(v % OX);
  const int n = (int)(v / OX);
  const long sx = (long)Y * Z * C, sy = (long)Z * C, sz = C;
  const long base = ((((long)n * X + 2 * ox) * Y + 2 * oy) * Z + 2 * oz) * (long)C + 4L * c4;
  float4 m = *reinterpret_cast<const float4*>(in + base);
  #pragma unroll
  for (int dd = 1; dd < 8; ++dd) {
    const int dxp = dd >> 2, dyp = (dd >> 1) & 1, dzp = dd & 1;
    const float4 t = *reinterpret_cast<const float4*>(in + base + dxp * sx + dyp * sy + dzp * sz);
    m.x = fmaxf(m.x, t.x); m.y = fmaxf(m.y, t.y);
    m.z = fmaxf(m.z, t.z); m.w = fmaxf(m.w, t.w);
  }
  const int c = 4 * c4;
  const float4 s4 = *reinterpret_cast<const float4*>(sc + c);
  const float4 h4 = *reinterpret_cast<const float4*>(sh + c);
  m.x = fmaxf(fmaf(m.x, s4.x, h4.x), 0.f);
  m.y = fmaxf(fmaf(m.y, s4.y, h4.y), 0.f);
  m.z = fmaxf(fmaf(m.z, s4.z, h4.z), 0.f);
  m.w = fmaxf(fmaf(m.w, s4.w, h4.w), 0.f);
  *reinterpret_cast<float4*>(out + idx * 4) = m;
}

__global__ __launch_bounds__(256) void head_kernel(
    const float* __restrict__ x8, const float* __restrict__ sc, const float* __restrict__ sh,
    const float* __restrict__ wl, const float* __restrict__ bl, float* __restrict__ out)
{
  const int n = blockIdx.x;
  const int c = threadIdx.x;     // 256
  __shared__ float h[256];
  const float* base = x8 + (long)n * 512 * 256;
  float s = 0.f;
  for (int v = 0; v < 512; ++v) s += base[(long)v * 256 + c];
  h[c] = fmaf(s * (1.f / 512.f), sc[c], sh[c]);
  __syncthreads();
  float acc = bl[c];
  for (int k = 0; k < 256; ++k) acc = fmaf(h[k], wl[(long)k * 256 + c], acc);
  out[(long)n * 256 + c] = acc;
}

// ---------------------------------------------------------------------------
extern "C" void kernel_launch(void* const* d_in, const int* in_sizes, int n_in,
                              void* d_out, int out_size, void* d_ws, size_t ws_size,
                              hipStream_t stream)
{
  const float* x = (const float*)d_in[0];
  const float* W[8];
  const float* G[8];
  const float* B[8];
  for (int i = 0; i < 8; ++i) {
    W[i] = (const float*)d_in[1 + 3 * i];
    G[i] = (const float*)d_in[2 + 3 * i];
    B[i] = (const float*)d_in[3 + 3 * i];
  }
  const float* wl = (const float*)d_in[25];
  const float* bl = (const float*)d_in[26];

  // workspace carve-up
  float* A    = (float*)d_ws;                 // 33,554,432 fl (128 MiB)
  float* Bb   = A + 33554432L;                // 16,777,216 fl ( 64 MiB)
  float* part = Bb + 16777216L;               // 131,072 fl
  float* scb  = part + 131072L;               // 256
  float* shb  = scb + 256;                    // 256
  f16*   wfb  = (f16*)(shb + 256);            // fragment-packed weights, ~13.4 MiB
  f16* wf[8];
  const int wfS[8] = {1, 2, 2, 4, 4, 8, 8, 8};
  const int wfG[8] = {4, 4, 8, 8, 16, 16, 16, 16};
  const int wfCR[8] = {3, 64, 64, 128, 128, 256, 256, 256};
  const int wfCO[8] = {64, 64, 128, 128, 256, 256, 256, 256};
  {
    long off = 0;
    for (int i = 0; i < 8; ++i) {
      wf[i] = wfb + off;
      off += 27L * wfS[i] * wfG[i] * 512;
    }
    if (ws_size < (size_t)((char*)(wfb + off) - (char*)d_ws)) return;  // fail loud, no OOB
  }

  // ---- weight prep ----
  for (int i = 0; i < 8; ++i) {
    const int ntot = 27 * wfS[i] * wfG[i] * 512;
    wprep<<<(ntot + 255) / 256, 256, 0, stream>>>(W[i], wf[i], wfS[i], wfG[i],
                                                  wfCR[i], wfCO[i], ntot);
  }

  auto stats = [&](const float* p0, const float* p1, long n0, long ntot, int C, int layer) {
    stats_partial<<<NB_STATS, 256, 0, stream>>>(p0, p1, n0, ntot, C, part);
    stats_final<<<1, 256, 0, stream>>>(part, NB_STATS, C, ntot, G[layer], B[layer], scb, shb);
  };
  auto bnrelu = [&](float* t, long nelem, int C) {
    long nb = (nelem / 4 + 255) / 256;
    if (nb > 8192) nb = 8192;
    bn_act<<<(unsigned)nb, 256, 0, stream>>>(t, t, scb, shb, nelem, C);
  };
  auto pool_aff = [&](const float* in, float* ob, int N, int Xd, int Yd, int Zd, int C) {
    const long nout = (long)N * (Xd / 2) * (Yd / 2) * (Zd / 2) * (C / 4);
    maxpool2_aff<<<(unsigned)((nout + 255) / 256), 256, 0, stream>>>(
        in, ob, N, Xd, Yd, Zd, C, scb, shb);
  };

  const long V64 = 262144;  // 64^3

  // ---- stage 1: 64^3 ----
  conv_mfma<32, 3, 64, 4, 1><<<dim3(2048, 1), 256, 0, stream>>>(x, wf[0], A, 64, 64, 64);
  stats(A, A, 2 * V64, 2 * V64, 64, 0);
  bnrelu(A, 2 * V64 * 64, 64);
  // conv2 split over batch: b0 -> Bb, b1 -> A[0:16M] (reads A[16M:32M], disjoint)
  conv_mfma<64, 64, 64, 4, 1><<<dim3(1024, 1), 256, 0, stream>>>(A, wf[1], Bb, 64, 64, 64);
  conv_mfma<64, 64, 64, 4, 1><<<dim3(1024, 1), 256, 0, stream>>>(A + V64 * 64, wf[1], A, 64, 64, 64);
  stats(Bb, A, V64, 2 * V64, 64, 1);
  {
    float* P = A + 16777216L;
    pool_aff(Bb, P,            1, 64, 64, 64, 64);
    pool_aff(A,  P + 2097152L, 1, 64, 64, 64, 64);
  }

  // ---- stage 2: 32^3 ----
  const float* P1 = A + 16777216L;
  conv_mfma<64, 64, 32, 2, 2><<<dim3(512, 1), 256, 0, stream>>>(P1, wf[2], A, 32, 32, 128);
  stats(A, A, 65536, 65536, 128, 2);
  bnrelu(A, 65536L * 128, 128);
  conv_mfma<128, 128, 32, 2, 2><<<dim3(512, 1), 256, 0, stream>>>(A, wf[3], Bb, 32, 32, 128);
  stats(Bb, Bb, 65536, 65536, 128, 3);
  float* Q = A + 8388608L;
  pool_aff(Bb, Q, 2, 32, 32, 32, 128);

  // ---- stage 3: 16^3 ----
  conv_mfma<128, 128, 16, 1, 2><<<dim3(128, 2), 128, 0, stream>>>(Q, wf[4], A, 16, 16, 256);
  stats(A, A, 8192, 8192, 256, 4);
  bnrelu(A, 8192L * 256, 256);
  conv_mfma<256, 256, 16, 1, 2><<<dim3(128, 2), 128, 0, stream>>>(A, wf[5], Bb, 16, 16, 256);
  stats(Bb, Bb, 8192, 8192, 256, 5);
  bnrelu(Bb, 8192L * 256, 256);
  float* A2 = A + 2097152L;
  conv_mfma<256, 256, 16, 1, 2><<<dim3(128, 2), 128, 0, stream>>>(Bb, wf[6], A2, 16, 16, 256);
  stats(A2, A2, 8192, 8192, 256, 6);
  float* R = A;
  pool_aff(A2, R, 2, 16, 16, 16, 256);

  // ---- stage 4: 8^3 ----
  conv_mfma<256, 256, 8, 1, 2><<<dim3(16, 2), 128, 0, stream>>>(R, wf[7], Bb, 8, 8, 256);
  stats(Bb, Bb, 1024, 1024, 256, 7);
  head_kernel<<<2, 256, 0, stream>>>(Bb, scb, shb, wl, bl, (float*)d_out);
}